// Round 8
// baseline (1030.856 us; speedup 1.0000x reference)
//
#include <hip/hip_runtime.h>
#include <hip/hip_bf16.h>
#include <stdint.h>

#define LROW 25600
#define NCH 256
#define LN_EPS 1e-5f

typedef float f32x4 __attribute__((ext_vector_type(4)));
typedef __bf16 bf16x8 __attribute__((ext_vector_type(8)));

__device__ __forceinline__ bf16x8 cvt8(f32x4 a, f32x4 b) {
  bf16x8 r;
  r[0] = (__bf16)a[0]; r[1] = (__bf16)a[1]; r[2] = (__bf16)a[2]; r[3] = (__bf16)a[3];
  r[4] = (__bf16)b[0]; r[5] = (__bf16)b[1]; r[6] = (__bf16)b[2]; r[7] = (__bf16)b[3];
  return r;
}

// raw barrier: drains LDS ops only, leaves prefetched global loads in flight
__device__ __forceinline__ void wg_bar() {
  asm volatile("s_waitcnt lgkmcnt(0)\n\ts_barrier" ::: "memory");
}

// ---------------------------------------------------------------------------
// Kernel A v8: identical to v7 (768 wgs = 96 XCD-pinned groups x 8 tiles,
// 256 thr, 4 waves 2x2, 64x64/wave, bf16 dbuf LDS, conflict-free swizzle)
// EXCEPT the epilogue: accumulators stored FRAGMENT-FLAT via f32x4 so each
// store instruction writes 1KB contiguous per wave (line-dense -> no
// eviction amplification). Layout: Pp[tile][ (i*4+j)*1024 + tid*4 + r ].
// ---------------------------------------------------------------------------
__global__ __launch_bounds__(256, 3) void gram_k(
    const float* __restrict__ qg, const float* __restrict__ kg,
    float* __restrict__ Pp,   // partials (in d_out): 96 groups x 8 tiles x 16384
    float* __restrict__ sq, float* __restrict__ sk) {
  __shared__ __align__(16) __bf16 lA[2][128 * 32];
  __shared__ __align__(16) __bf16 lB[2][128 * 32];

  const int bid = blockIdx.x;
  const int xcd = bid & 7, s2 = bid >> 3;   // consecutive bids round-robin XCDs
  const int tile = s2 & 7, gslot = s2 >> 3; // gslot 0..11
  const int g = gslot * 8 + xcd;            // group 0..95, fixed XCD per group
  const int b = g / 12, ks = g % 12;
  const int mat = tile >> 2;                // 0: G = q x k, 1: Gkk = k x k
  const int ri = (tile >> 1) & 1, ci = tile & 1;
  const int c0 = (800 * ks) / 12, c1 = (800 * (ks + 1)) / 12;
  const int nc = c1 - c0;                   // 66 or 67 chunks of K=32

  const int tid = threadIdx.x;
  const int w = tid >> 6, lane = tid & 63;
  const int wr = w >> 1, wc = w & 1;
  const int lr = lane & 15, gq = lane >> 4;

  const float* Abase = (mat ? kg : qg) + (size_t)b * NCH * LROW + (size_t)(ri * 128) * LROW;
  const float* Bbase = kg + (size_t)b * NCH * LROW + (size_t)(ci * 128) * LROW;

  // staging: thread owns (row rowS = tid>>1, 16-float half h = tid&1)
  const int rowS = tid >> 1, h = tid & 1;
  const float* Ap = Abase + (size_t)rowS * LROW + h * 16 + (size_t)c0 * 32;
  const float* Bp = Bbase + (size_t)rowS * LROW + h * 16 + (size_t)c0 * 32;
  const int swz = (rowS >> 1) & 3;  // conflict-free (r7-verified: 0 conflicts)
  const int d0 = rowS * 32 + (((2 * h) ^ swz) * 8);
  const int d1 = rowS * 32 + (((2 * h + 1) ^ swz) * 8);

  const f32x4 zero = {0.f, 0.f, 0.f, 0.f};
  f32x4 acc[4][4];
#pragma unroll
  for (int i = 0; i < 4; ++i)
#pragma unroll
    for (int j = 0; j < 4; ++j) acc[i][j] = zero;

  float rsum = 0.f;
  f32x4 bA[8], bB[8];

  auto LOADG = [&](int c, f32x4* d) {
    const float* pa = Ap + (size_t)c * 32;
#pragma unroll
    for (int i = 0; i < 4; ++i) d[i] = *(const f32x4*)(pa + i * 4);
    const float* pb = Bp + (size_t)c * 32;
#pragma unroll
    for (int i = 0; i < 4; ++i) d[4 + i] = *(const f32x4*)(pb + i * 4);
  };
  auto WRITE = [&](f32x4* d, int buf) {
#pragma unroll
    for (int e = 0; e < 4; ++e)
      rsum += d[0][e] + d[1][e] + d[2][e] + d[3][e];  // A-panel row partial
    *(bf16x8*)(&lA[buf][d0]) = cvt8(d[0], d[1]);
    *(bf16x8*)(&lA[buf][d1]) = cvt8(d[2], d[3]);
    *(bf16x8*)(&lB[buf][d0]) = cvt8(d[4], d[5]);
    *(bf16x8*)(&lB[buf][d1]) = cvt8(d[6], d[7]);
  };
  auto COMPUTE = [&](int buf) {
    bf16x8 af[4];
#pragma unroll
    for (int i = 0; i < 4; ++i) {
      const int row = wr * 64 + i * 16 + lr;
      af[i] = *(const bf16x8*)(&lA[buf][row * 32 + ((gq ^ ((row >> 1) & 3)) * 8)]);
    }
#pragma unroll
    for (int j = 0; j < 4; ++j) {
      const int row = wc * 64 + j * 16 + lr;
      bf16x8 bfj = *(const bf16x8*)(&lB[buf][row * 32 + ((gq ^ ((row >> 1) & 3)) * 8)]);
#pragma unroll
      for (int i = 0; i < 4; ++i)
        acc[i][j] = __builtin_amdgcn_mfma_f32_16x16x32_bf16(af[i], bfj, acc[i][j], 0, 0, 0);
    }
  };

  LOADG(0, bA);
  LOADG(1, bB);
  int cc = 0;
  for (; cc + 2 <= nc; cc += 2) {
    WRITE(bA, 0);
    wg_bar();
    if (cc + 2 < nc) LOADG(cc + 2, bA);
    COMPUTE(0);
    WRITE(bB, 1);
    wg_bar();
    if (cc + 3 < nc) LOADG(cc + 3, bB);
    COMPUTE(1);
  }
  if (cc < nc) { WRITE(bA, 0); wg_bar(); COMPUTE(0); }

  // row sums: pair-reduce, one atomic per row, once per (mat,row) via ci==0
  rsum += __shfl_xor(rsum, 1);
  if (h == 0 && ci == 0)
    atomicAdd((mat ? sk : sq) + b * NCH + ri * 128 + rowS, rsum);

  // fragment-flat epilogue: 16 x f32x4, each instr = 1KB contiguous per wave
  float* Gout = Pp + ((size_t)(b * 12 + ks) * 8 + tile) * 16384;
#pragma unroll
  for (int i = 0; i < 4; ++i)
#pragma unroll
    for (int j = 0; j < 4; ++j)
      *(f32x4*)(Gout + (i * 4 + j) * 1024 + tid * 4) = acc[i][j];
}

// ---------------------------------------------------------------------------
// reduce partials (fragment-flat) over 12 kslices -> G[b] / Gkk[b].
// 1024 wgs x 256 thr; each thread sums 12 x f32x4 (coalesced reads: lanes
// cover 1KB contiguous) then inverts the fragment map and scatters 4 floats.
// ---------------------------------------------------------------------------
__global__ __launch_bounds__(256) void reduce_k(
    const float* __restrict__ Pp, float* __restrict__ G, float* __restrict__ Gkk) {
  const int gidx = blockIdx.x * 256 + threadIdx.x;  // 0 .. 262143
  const int p = (gidx & 4095) * 4;                  // flat pos within tile
  const int tg = gidx >> 12;                        // 0..63 = (b, tile)
  const int b = tg >> 3, tile = tg & 7;
  const int mat = tile >> 2, ri = (tile >> 1) & 1, ci = tile & 1;

  f32x4 a = {0.f, 0.f, 0.f, 0.f};
#pragma unroll
  for (int ks = 0; ks < 12; ++ks)
    a += *(const f32x4*)(Pp + ((size_t)(b * 12 + ks) * 8 + tile) * 16384 + p);

  // invert fragment map: p = (i*4+j)*1024 + tid*4 + r
  const int vg = p >> 10, i = vg >> 2, j = vg & 3;
  const int tid = (p & 1023) >> 2;
  const int w = tid >> 6, lane = tid & 63;
  const int wr = w >> 1, wc = w & 1;
  const int lr = lane & 15, gq = lane >> 4;
  const int row0 = ri * 128 + wr * 64 + i * 16 + gq * 4;
  const int col = ci * 128 + wc * 64 + j * 16 + lr;

  float* dst = (mat ? Gkk : G) + (size_t)b * 65536;
#pragma unroll
  for (int r = 0; r < 4; ++r) dst[(size_t)(row0 + r) * 256 + col] = a[r];
}

// ---------------------------------------------------------------------------
// Kernel B1: scores -> softmax -> M = A*Wv_h, cvec
// ---------------------------------------------------------------------------
__global__ __launch_bounds__(256) void attn_k(
    const float* __restrict__ G, const float* __restrict__ sq,
    const float* __restrict__ sk,
    const float* __restrict__ Wq, const float* __restrict__ bq,
    const float* __restrict__ Wk, const float* __restrict__ bk,
    const float* __restrict__ Wv, const float* __restrict__ bv,
    float* __restrict__ M, float* __restrict__ cvec) {
  __shared__ float Wql[32][257];
  __shared__ float Wkl[32][257];
  __shared__ float QGl[32][257];
  __shared__ float Sl[32][33];
  __shared__ float Al[32][33];
  __shared__ float ul[32], wl[32];
  const int b = blockIdx.x >> 3, hh = blockIdx.x & 7;
  const int t = threadIdx.x;
  const float* Gb = G + (size_t)b * 65536;

  for (int i = 0; i < 32; ++i) {
    int idx = i * 256 + t;
    int d = idx >> 8, c = idx & 255;
    Wql[d][c] = Wq[(hh * 32 + d) * 256 + c];
    Wkl[d][c] = Wk[(hh * 32 + d) * 256 + c];
  }
  __syncthreads();
  {
    float a[32];
#pragma unroll
    for (int d = 0; d < 32; ++d) a[d] = 0.f;
#pragma unroll 8
    for (int c = 0; c < 256; ++c) {
      float gv = Gb[c * 256 + t];
#pragma unroll
      for (int d = 0; d < 32; ++d) a[d] += Wql[d][c] * gv;
    }
    for (int d = 0; d < 32; ++d) QGl[d][t] = a[d];
  }
  if (t < 32) {
    float u = 0.f, wv = 0.f;
#pragma unroll 8
    for (int c = 0; c < 256; ++c) {
      u += Wql[t][c] * sq[b * 256 + c];
      wv += Wkl[t][c] * sk[b * 256 + c];
    }
    ul[t] = u; wl[t] = wv;
  }
  __syncthreads();
  for (int i = 0; i < 4; ++i) {
    int idx = i * 256 + t;
    int d = idx >> 5, e = idx & 31;
    float sv = 0.f;
#pragma unroll 8
    for (int c = 0; c < 256; ++c) sv += QGl[d][c] * Wkl[e][c];
    float bqd = bq[hh * 32 + d], bke = bk[hh * 32 + e];
    Sl[d][e] = (sv + ul[d] * bke + bqd * wl[e] + 25600.f * bqd * bke) * (1.f / 16.f);
  }
  __syncthreads();
  if (t < 32) {
    float m = -1e30f;
    for (int e = 0; e < 32; ++e) m = fmaxf(m, Sl[t][e]);
    float ssum = 0.f;
    for (int e = 0; e < 32; ++e) { float pp = __expf(Sl[t][e] - m); Al[t][e] = pp; ssum += pp; }
    float is = 1.f / ssum;
    for (int e = 0; e < 32; ++e) Al[t][e] *= is;
  }
  __syncthreads();
  {
    float a[32];
#pragma unroll
    for (int d = 0; d < 32; ++d) a[d] = 0.f;
#pragma unroll 4
    for (int e = 0; e < 32; ++e) {
      float wv = Wv[(hh * 32 + e) * 256 + t];
#pragma unroll
      for (int d = 0; d < 32; ++d) a[d] += Al[d][e] * wv;
    }
    for (int d = 0; d < 32; ++d) M[((size_t)b * 256 + hh * 32 + d) * 256 + t] = a[d];
  }
  if (t < 32) {
    float cv = 0.f;
    for (int e = 0; e < 32; ++e) cv += Al[t][e] * bv[hh * 32 + e];
    cvec[b * 256 + hh * 32 + t] = cv;
  }
}

// ---------------------------------------------------------------------------
// Kernel B2: LN stats via quadratic form qf[c] = M Gkk M^T diag
// ---------------------------------------------------------------------------
__global__ __launch_bounds__(256) void stats_k(
    const float* __restrict__ Gkk, const float* __restrict__ M,
    const float* __restrict__ sk, const float* __restrict__ cvec,
    float* __restrict__ mu, float* __restrict__ inv) {
  __shared__ float Ml[32][257];
  __shared__ float Ql[32][257];
  const int b = blockIdx.x >> 3, cb = blockIdx.x & 7;
  const int t = threadIdx.x;
  const float* Gk = Gkk + (size_t)b * 65536;
  for (int i = 0; i < 32; ++i) {
    int idx = i * 256 + t;
    Ml[idx >> 8][idx & 255] = M[((size_t)b * 256 + cb * 32 + (idx >> 8)) * 256 + (idx & 255)];
  }
  __syncthreads();
  {
    float a[32];
#pragma unroll
    for (int c = 0; c < 32; ++c) a[c] = 0.f;
#pragma unroll 8
    for (int cc = 0; cc < 256; ++cc) {
      float gv = Gk[cc * 256 + t];
#pragma unroll
      for (int c = 0; c < 32; ++c) a[c] += Ml[c][cc] * gv;
    }
    for (int c = 0; c < 32; ++c) Ql[c][t] = a[c];
  }
  __syncthreads();
  if (t < 32) {
    float qf = 0.f, msk = 0.f;
#pragma unroll 8
    for (int j = 0; j < 256; ++j) {
      qf += Ql[t][j] * Ml[t][j];
      msk += Ml[t][j] * sk[b * 256 + j];
    }
    int c = cb * 32 + t;
    float cv = cvec[b * 256 + c];
    float muv = msk * (1.f / 25600.f) + cv;
    float sum2 = qf + 2.f * cv * msk + 25600.f * cv * cv;
    float var = sum2 * (1.f / 25600.f) - muv * muv;
    mu[b * 256 + c] = muv;
    inv[b * 256 + c] = rsqrtf(var + LN_EPS);
  }
}

// ---------------------------------------------------------------------------
// Kernel B3: P = (Wo o inv) M (bf16), t1, wsum
// ---------------------------------------------------------------------------
__global__ __launch_bounds__(256) void pmat_k(
    const float* __restrict__ M, const float* __restrict__ Wo,
    const float* __restrict__ inv, const float* __restrict__ cvec,
    const float* __restrict__ mu, __bf16* __restrict__ Pb,
    float* __restrict__ t1, float* __restrict__ wsum) {
  __shared__ float Wol[32][257];
  __shared__ float invl[256];
  const int b = blockIdx.x >> 3, ob = blockIdx.x & 7;
  const int t = threadIdx.x;
  invl[t] = inv[b * 256 + t];
  __syncthreads();
  for (int i = 0; i < 32; ++i) {
    int idx = i * 256 + t;
    int o = idx >> 8, c = idx & 255;
    Wol[o][c] = Wo[(ob * 32 + o) * 256 + c] * invl[c];
  }
  __syncthreads();
  {
    float a[32];
#pragma unroll
    for (int o = 0; o < 32; ++o) a[o] = 0.f;
#pragma unroll 8
    for (int c = 0; c < 256; ++c) {
      float m = M[((size_t)b * 256 + c) * 256 + t];
#pragma unroll
      for (int o = 0; o < 32; ++o) a[o] += Wol[o][c] * m;
    }
    for (int o = 0; o < 32; ++o)
      Pb[((size_t)b * 256 + ob * 32 + o) * 256 + t] = (__bf16)a[o];
  }
  if (t < 32) {
    float s1 = 0.f, s2 = 0.f;
#pragma unroll 8
    for (int c = 0; c < 256; ++c) {
      s1 += Wol[t][c] * (cvec[b * 256 + c] - mu[b * 256 + c]);
      s2 += Wo[(ob * 32 + t) * 256 + c];
    }
    t1[b * 256 + ob * 32 + t] = s1;
    wsum[b * 256 + ob * 32 + t] = s2;
  }
}

// ---------------------------------------------------------------------------
// Kernel C: out = gamma*(P key + t1) + beta*wsum + bo (fused LN + conv).
// 1600 wgs batch-pinned to XCDs, 512 thr, 8 waves (4x2), 64KB LDS, 2 wg/CU.
// ---------------------------------------------------------------------------
__global__ __launch_bounds__(512, 4) void outf_k(
    const float* __restrict__ key, const __bf16* __restrict__ Pb,
    const float* __restrict__ t1, const float* __restrict__ wsum,
    const float* __restrict__ bo, const float* __restrict__ gamma,
    const float* __restrict__ beta, float* __restrict__ out) {
  __shared__ __align__(16) __bf16 Bt[128 * 256];  // [l][c], XOR-swizzled, 64KB
  const int bid = blockIdx.x;
  const int b = bid & 7, lt = bid >> 3, l0 = lt * 128;  // batch -> XCD pin
  const int tid = threadIdx.x, w = tid >> 6, lane = tid & 63;
  const int wr = w >> 1, wc = w & 1;
  const int lr = lane & 15, g = lane >> 4;
  const float* Kb = key + (size_t)b * NCH * LROW;

  // stage: thread = (channel c, l-half seg); 16x f32x4 contiguous per lane
  {
    const int c = tid & 255, seg = tid >> 8;
    const int uc = c >> 3, cb2 = (c & 7) * 2;
    const float* src = Kb + (size_t)c * LROW + l0 + seg * 64;
#pragma unroll
    for (int i = 0; i < 16; ++i) {
      f32x4 v = *(const f32x4*)(src + i * 4);
#pragma unroll
      for (int j = 0; j < 4; ++j) {
        const int l = seg * 64 + i * 4 + j;
        *(__bf16*)((char*)Bt + l * 512 + ((uc ^ (l & 7)) << 4) + cb2) = (__bf16)v[j];
      }
    }
  }
  __syncthreads();

  const f32x4 zero = {0.f, 0.f, 0.f, 0.f};
  f32x4 acc[4][4];
#pragma unroll
  for (int i = 0; i < 4; ++i)
#pragma unroll
    for (int j = 0; j < 4; ++j) acc[i][j] = zero;

  const __bf16* Pbase = Pb + (size_t)b * 65536;
#pragma unroll
  for (int ks = 0; ks < 8; ++ks) {
    bf16x8 af[4];
#pragma unroll
    for (int i = 0; i < 4; ++i) {
      const int row = wr * 64 + i * 16 + lr;
      af[i] = *(const bf16x8*)(Pbase + (size_t)row * 256 + ks * 32 + g * 8);
    }
#pragma unroll
    for (int j = 0; j < 4; ++j) {
      const int col = wc * 64 + j * 16 + lr;
      const int unit = ks * 4 + g;
      bf16x8 bfj = *(const bf16x8*)((const char*)Bt + col * 512 + ((unit ^ (col & 7)) << 4));
#pragma unroll
      for (int i = 0; i < 4; ++i)
        acc[i][j] = __builtin_amdgcn_mfma_f32_16x16x32_bf16(af[i], bfj, acc[i][j], 0, 0, 0);
    }
  }

  // lean epilogue: i/r outer (row scalars live briefly), j inner
#pragma unroll
  for (int i = 0; i < 4; ++i)
#pragma unroll
    for (int r = 0; r < 4; ++r) {
      const int row = wr * 64 + i * 16 + g * 4 + r;
      const float t1v = t1[b * 256 + row];
      const float wsv = wsum[b * 256 + row];
      const float bov = bo[row];
      const size_t ro = ((size_t)b * 256 + row) * LROW + l0;
#pragma unroll
      for (int j = 0; j < 4; ++j) {
        const int cl = wc * 64 + j * 16 + lr;
        out[ro + cl] = gamma[l0 + cl] * (acc[i][j][r] + t1v) + beta[l0 + cl] * wsv + bov;
      }
    }
}

// ---------------------------------------------------------------------------
extern "C" void kernel_launch(void* const* d_in, const int* in_sizes, int n_in,
                              void* d_out, int out_size, void* d_ws, size_t ws_size,
                              hipStream_t stream) {
  const float* query = (const float*)d_in[0];
  const float* key   = (const float*)d_in[1];
  const float* Wq = (const float*)d_in[2];
  const float* bq = (const float*)d_in[3];
  const float* Wk = (const float*)d_in[4];
  const float* bk = (const float*)d_in[5];
  const float* Wv = (const float*)d_in[6];
  const float* bv = (const float*)d_in[7];
  const float* Wo = (const float*)d_in[8];
  const float* bo = (const float*)d_in[9];
  const float* gamma = (const float*)d_in[10];
  const float* beta  = (const float*)d_in[11];
  float* out = (float*)d_out;

  // Workspace: base layout only (~7.4MB)
  float* ws = (float*)d_ws;
  float* G    = ws;                  // 524288
  float* Gkk  = G + 524288;          // 524288
  float* sq   = Gkk + 524288;        // 2048
  float* sk   = sq + 2048;           // 2048
  float* M    = sk + 2048;           // 524288
  float* cvec = M + 524288;          // 2048
  float* mu   = cvec + 2048;         // 2048
  float* inv  = mu + 2048;           // 2048
  float* t1   = inv + 2048;          // 2048
  float* wsum = t1 + 2048;           // 2048
  __bf16* Pb  = (__bf16*)(wsum + 2048);  // 524288 bf16

  // Gram partials live in D_OUT (50MB of its 209MB), fragment-flat layout;
  // outf_k overwrites all of d_out at the very end.
  float* Pp = out;

  hipMemsetAsync(sq, 0, 4096 * sizeof(float), stream);  // sq+sk (row-sum atomics)
  gram_k<<<768, 256, 0, stream>>>(query, key, Pp, sq, sk);
  reduce_k<<<1024, 256, 0, stream>>>(Pp, G, Gkk);
  attn_k<<<64, 256, 0, stream>>>(G, sq, sk, Wq, bq, Wk, bk, Wv, bv, M, cvec);
  stats_k<<<64, 256, 0, stream>>>(Gkk, M, sk, cvec, mu, inv);
  pmat_k<<<64, 256, 0, stream>>>(M, Wo, inv, cvec, mu, Pb, t1, wsum);
  outf_k<<<1600, 512, 0, stream>>>(key, Pb, t1, wsum, bo, gamma, beta, out);
}

// Round 9
// 703.769 us; speedup vs baseline: 1.4648x; 1.4648x over previous
//
#include <hip/hip_runtime.h>
#include <hip/hip_bf16.h>
#include <stdint.h>

#define LROW 25600
#define NCH 256
#define LN_EPS 1e-5f

typedef float f32x4 __attribute__((ext_vector_type(4)));
typedef __bf16 bf16x8 __attribute__((ext_vector_type(8)));

__device__ __forceinline__ bf16x8 cvt8(f32x4 a, f32x4 b) {
  bf16x8 r;
  r[0] = (__bf16)a[0]; r[1] = (__bf16)a[1]; r[2] = (__bf16)a[2]; r[3] = (__bf16)a[3];
  r[4] = (__bf16)b[0]; r[5] = (__bf16)b[1]; r[6] = (__bf16)b[2]; r[7] = (__bf16)b[3];
  return r;
}

// raw barrier: drains LDS ops only, leaves prefetched global loads in flight
__device__ __forceinline__ void wg_bar() {
  asm volatile("s_waitcnt lgkmcnt(0)\n\ts_barrier" ::: "memory");
}

// ---------------------------------------------------------------------------
// Kernel A v9: body identical to v8; register budget fixed.
// 512 wgs = 64 XCD-pinned groups (8b x 8 kslices, 100 chunks) x 8 tiles
// (4 G + 4 Gkk 128x128 quadrants). 256 thr, 4 waves 2x2, 64x64/wave.
// __launch_bounds__(256,2): cap 256 regs/wave -> acc64 + staging64 + addr
// (~212) fits WITHOUT SPILL (r4-r8's hidden 850MB scratch writeback).
// 2 wg/CU exactly (512 = 2 x 256 CUs), one generation, no tail.
// ---------------------------------------------------------------------------
__global__ __launch_bounds__(256, 2) void gram_k(
    const float* __restrict__ qg, const float* __restrict__ kg,
    float* __restrict__ Pp,   // partials (in d_out): 64 groups x 8 tiles x 16384
    float* __restrict__ sq, float* __restrict__ sk) {
  __shared__ __align__(16) __bf16 lA[2][128 * 32];
  __shared__ __align__(16) __bf16 lB[2][128 * 32];

  const int bid = blockIdx.x;
  const int xcd = bid & 7, s2 = bid >> 3;   // consecutive bids round-robin XCDs
  const int tile = s2 & 7, gslot = s2 >> 3; // gslot 0..7
  const int g = gslot * 8 + xcd;            // group 0..63, fixed XCD per group
  const int b = g >> 3, ks = g & 7;
  const int mat = tile >> 2;                // 0: G = q x k, 1: Gkk = k x k
  const int ri = (tile >> 1) & 1, ci = tile & 1;
  const int c0 = ks * 100;
  const int nc = 100;                       // chunks of K=32, even -> clean pairs

  const int tid = threadIdx.x;
  const int w = tid >> 6, lane = tid & 63;
  const int wr = w >> 1, wc = w & 1;
  const int lr = lane & 15, gq = lane >> 4;

  const float* Abase = (mat ? kg : qg) + (size_t)b * NCH * LROW + (size_t)(ri * 128) * LROW;
  const float* Bbase = kg + (size_t)b * NCH * LROW + (size_t)(ci * 128) * LROW;

  // staging: thread owns (row rowS = tid>>1, 16-float half h = tid&1)
  const int rowS = tid >> 1, h = tid & 1;
  const float* Ap = Abase + (size_t)rowS * LROW + h * 16 + (size_t)c0 * 32;
  const float* Bp = Bbase + (size_t)rowS * LROW + h * 16 + (size_t)c0 * 32;
  const int swz = (rowS >> 1) & 3;  // conflict-free (r7/r8-verified: 0 conflicts)
  const int d0 = rowS * 32 + (((2 * h) ^ swz) * 8);
  const int d1 = rowS * 32 + (((2 * h + 1) ^ swz) * 8);

  const f32x4 zero = {0.f, 0.f, 0.f, 0.f};
  f32x4 acc[4][4];
#pragma unroll
  for (int i = 0; i < 4; ++i)
#pragma unroll
    for (int j = 0; j < 4; ++j) acc[i][j] = zero;

  float rsum = 0.f;
  f32x4 bA[8], bB[8];

  auto LOADG = [&](int c, f32x4* d) {
    const float* pa = Ap + (size_t)c * 32;
#pragma unroll
    for (int i = 0; i < 4; ++i) d[i] = *(const f32x4*)(pa + i * 4);
    const float* pb = Bp + (size_t)c * 32;
#pragma unroll
    for (int i = 0; i < 4; ++i) d[4 + i] = *(const f32x4*)(pb + i * 4);
  };
  auto WRITE = [&](f32x4* d, int buf) {
#pragma unroll
    for (int e = 0; e < 4; ++e)
      rsum += d[0][e] + d[1][e] + d[2][e] + d[3][e];  // A-panel row partial
    *(bf16x8*)(&lA[buf][d0]) = cvt8(d[0], d[1]);
    *(bf16x8*)(&lA[buf][d1]) = cvt8(d[2], d[3]);
    *(bf16x8*)(&lB[buf][d0]) = cvt8(d[4], d[5]);
    *(bf16x8*)(&lB[buf][d1]) = cvt8(d[6], d[7]);
  };
  auto COMPUTE = [&](int buf) {
    bf16x8 af[4];
#pragma unroll
    for (int i = 0; i < 4; ++i) {
      const int row = wr * 64 + i * 16 + lr;
      af[i] = *(const bf16x8*)(&lA[buf][row * 32 + ((gq ^ ((row >> 1) & 3)) * 8)]);
    }
#pragma unroll
    for (int j = 0; j < 4; ++j) {
      const int row = wc * 64 + j * 16 + lr;
      bf16x8 bfj = *(const bf16x8*)(&lB[buf][row * 32 + ((gq ^ ((row >> 1) & 3)) * 8)]);
#pragma unroll
      for (int i = 0; i < 4; ++i)
        acc[i][j] = __builtin_amdgcn_mfma_f32_16x16x32_bf16(af[i], bfj, acc[i][j], 0, 0, 0);
    }
  };

  LOADG(0, bA);
  LOADG(1, bB);
  int cc = 0;
  for (; cc + 2 <= nc; cc += 2) {
    WRITE(bA, 0);
    wg_bar();
    if (cc + 2 < nc) LOADG(cc + 2, bA);
    COMPUTE(0);
    WRITE(bB, 1);
    wg_bar();
    if (cc + 3 < nc) LOADG(cc + 3, bB);
    COMPUTE(1);
  }

  // row sums: pair-reduce, one atomic per row, once per (mat,row) via ci==0
  rsum += __shfl_xor(rsum, 1);
  if (h == 0 && ci == 0)
    atomicAdd((mat ? sk : sq) + b * NCH + ri * 128 + rowS, rsum);

  // fragment-flat epilogue: 16 x f32x4, each instr = 1KB contiguous per wave
  float* Gout = Pp + ((size_t)(b * 8 + ks) * 8 + tile) * 16384;
#pragma unroll
  for (int i = 0; i < 4; ++i)
#pragma unroll
    for (int j = 0; j < 4; ++j)
      *(f32x4*)(Gout + (i * 4 + j) * 1024 + tid * 4) = acc[i][j];
}

// ---------------------------------------------------------------------------
// reduce partials (fragment-flat) over 8 kslices -> G[b] / Gkk[b].
// 1024 wgs x 256 thr; thread sums 8 x f32x4 (coalesced) then inverts the
// fragment map and scatters 4 floats.
// ---------------------------------------------------------------------------
__global__ __launch_bounds__(256) void reduce_k(
    const float* __restrict__ Pp, float* __restrict__ G, float* __restrict__ Gkk) {
  const int gidx = blockIdx.x * 256 + threadIdx.x;  // 0 .. 262143
  const int p = (gidx & 4095) * 4;                  // flat pos within tile
  const int tg = gidx >> 12;                        // 0..63 = (b, tile)
  const int b = tg >> 3, tile = tg & 7;
  const int mat = tile >> 2, ri = (tile >> 1) & 1, ci = tile & 1;

  f32x4 a = {0.f, 0.f, 0.f, 0.f};
#pragma unroll
  for (int ks = 0; ks < 8; ++ks)
    a += *(const f32x4*)(Pp + ((size_t)(b * 8 + ks) * 8 + tile) * 16384 + p);

  // invert fragment map: p = (i*4+j)*1024 + tid*4 + r
  const int vg = p >> 10, i = vg >> 2, j = vg & 3;
  const int tid = (p & 1023) >> 2;
  const int w = tid >> 6, lane = tid & 63;
  const int wr = w >> 1, wc = w & 1;
  const int lr = lane & 15, gq = lane >> 4;
  const int row0 = ri * 128 + wr * 64 + i * 16 + gq * 4;
  const int col = ci * 128 + wc * 64 + j * 16 + lr;

  float* dst = (mat ? Gkk : G) + (size_t)b * 65536;
#pragma unroll
  for (int r = 0; r < 4; ++r) dst[(size_t)(row0 + r) * 256 + col] = a[r];
}

// ---------------------------------------------------------------------------
// Kernel B1: scores -> softmax -> M = A*Wv_h, cvec
// ---------------------------------------------------------------------------
__global__ __launch_bounds__(256) void attn_k(
    const float* __restrict__ G, const float* __restrict__ sq,
    const float* __restrict__ sk,
    const float* __restrict__ Wq, const float* __restrict__ bq,
    const float* __restrict__ Wk, const float* __restrict__ bk,
    const float* __restrict__ Wv, const float* __restrict__ bv,
    float* __restrict__ M, float* __restrict__ cvec) {
  __shared__ float Wql[32][257];
  __shared__ float Wkl[32][257];
  __shared__ float QGl[32][257];
  __shared__ float Sl[32][33];
  __shared__ float Al[32][33];
  __shared__ float ul[32], wl[32];
  const int b = blockIdx.x >> 3, hh = blockIdx.x & 7;
  const int t = threadIdx.x;
  const float* Gb = G + (size_t)b * 65536;

  for (int i = 0; i < 32; ++i) {
    int idx = i * 256 + t;
    int d = idx >> 8, c = idx & 255;
    Wql[d][c] = Wq[(hh * 32 + d) * 256 + c];
    Wkl[d][c] = Wk[(hh * 32 + d) * 256 + c];
  }
  __syncthreads();
  {
    float a[32];
#pragma unroll
    for (int d = 0; d < 32; ++d) a[d] = 0.f;
#pragma unroll 8
    for (int c = 0; c < 256; ++c) {
      float gv = Gb[c * 256 + t];
#pragma unroll
      for (int d = 0; d < 32; ++d) a[d] += Wql[d][c] * gv;
    }
    for (int d = 0; d < 32; ++d) QGl[d][t] = a[d];
  }
  if (t < 32) {
    float u = 0.f, wv = 0.f;
#pragma unroll 8
    for (int c = 0; c < 256; ++c) {
      u += Wql[t][c] * sq[b * 256 + c];
      wv += Wkl[t][c] * sk[b * 256 + c];
    }
    ul[t] = u; wl[t] = wv;
  }
  __syncthreads();
  for (int i = 0; i < 4; ++i) {
    int idx = i * 256 + t;
    int d = idx >> 5, e = idx & 31;
    float sv = 0.f;
#pragma unroll 8
    for (int c = 0; c < 256; ++c) sv += QGl[d][c] * Wkl[e][c];
    float bqd = bq[hh * 32 + d], bke = bk[hh * 32 + e];
    Sl[d][e] = (sv + ul[d] * bke + bqd * wl[e] + 25600.f * bqd * bke) * (1.f / 16.f);
  }
  __syncthreads();
  if (t < 32) {
    float m = -1e30f;
    for (int e = 0; e < 32; ++e) m = fmaxf(m, Sl[t][e]);
    float ssum = 0.f;
    for (int e = 0; e < 32; ++e) { float pp = __expf(Sl[t][e] - m); Al[t][e] = pp; ssum += pp; }
    float is = 1.f / ssum;
    for (int e = 0; e < 32; ++e) Al[t][e] *= is;
  }
  __syncthreads();
  {
    float a[32];
#pragma unroll
    for (int d = 0; d < 32; ++d) a[d] = 0.f;
#pragma unroll 4
    for (int e = 0; e < 32; ++e) {
      float wv = Wv[(hh * 32 + e) * 256 + t];
#pragma unroll
      for (int d = 0; d < 32; ++d) a[d] += Al[d][e] * wv;
    }
    for (int d = 0; d < 32; ++d) M[((size_t)b * 256 + hh * 32 + d) * 256 + t] = a[d];
  }
  if (t < 32) {
    float cv = 0.f;
    for (int e = 0; e < 32; ++e) cv += Al[t][e] * bv[hh * 32 + e];
    cvec[b * 256 + hh * 32 + t] = cv;
  }
}

// ---------------------------------------------------------------------------
// Kernel B2: LN stats via quadratic form qf[c] = M Gkk M^T diag
// ---------------------------------------------------------------------------
__global__ __launch_bounds__(256) void stats_k(
    const float* __restrict__ Gkk, const float* __restrict__ M,
    const float* __restrict__ sk, const float* __restrict__ cvec,
    float* __restrict__ mu, float* __restrict__ inv) {
  __shared__ float Ml[32][257];
  __shared__ float Ql[32][257];
  const int b = blockIdx.x >> 3, cb = blockIdx.x & 7;
  const int t = threadIdx.x;
  const float* Gk = Gkk + (size_t)b * 65536;
  for (int i = 0; i < 32; ++i) {
    int idx = i * 256 + t;
    Ml[idx >> 8][idx & 255] = M[((size_t)b * 256 + cb * 32 + (idx >> 8)) * 256 + (idx & 255)];
  }
  __syncthreads();
  {
    float a[32];
#pragma unroll
    for (int c = 0; c < 32; ++c) a[c] = 0.f;
#pragma unroll 8
    for (int cc = 0; cc < 256; ++cc) {
      float gv = Gk[cc * 256 + t];
#pragma unroll
      for (int c = 0; c < 32; ++c) a[c] += Ml[c][cc] * gv;
    }
    for (int c = 0; c < 32; ++c) Ql[c][t] = a[c];
  }
  __syncthreads();
  if (t < 32) {
    float qf = 0.f, msk = 0.f;
#pragma unroll 8
    for (int j = 0; j < 256; ++j) {
      qf += Ql[t][j] * Ml[t][j];
      msk += Ml[t][j] * sk[b * 256 + j];
    }
    int c = cb * 32 + t;
    float cv = cvec[b * 256 + c];
    float muv = msk * (1.f / 25600.f) + cv;
    float sum2 = qf + 2.f * cv * msk + 25600.f * cv * cv;
    float var = sum2 * (1.f / 25600.f) - muv * muv;
    mu[b * 256 + c] = muv;
    inv[b * 256 + c] = rsqrtf(var + LN_EPS);
  }
}

// ---------------------------------------------------------------------------
// Kernel B3: P = (Wo o inv) M (bf16), t1, wsum
// ---------------------------------------------------------------------------
__global__ __launch_bounds__(256) void pmat_k(
    const float* __restrict__ M, const float* __restrict__ Wo,
    const float* __restrict__ inv, const float* __restrict__ cvec,
    const float* __restrict__ mu, __bf16* __restrict__ Pb,
    float* __restrict__ t1, float* __restrict__ wsum) {
  __shared__ float Wol[32][257];
  __shared__ float invl[256];
  const int b = blockIdx.x >> 3, ob = blockIdx.x & 7;
  const int t = threadIdx.x;
  invl[t] = inv[b * 256 + t];
  __syncthreads();
  for (int i = 0; i < 32; ++i) {
    int idx = i * 256 + t;
    int o = idx >> 8, c = idx & 255;
    Wol[o][c] = Wo[(ob * 32 + o) * 256 + c] * invl[c];
  }
  __syncthreads();
  {
    float a[32];
#pragma unroll
    for (int o = 0; o < 32; ++o) a[o] = 0.f;
#pragma unroll 8
    for (int c = 0; c < 256; ++c) {
      float m = M[((size_t)b * 256 + c) * 256 + t];
#pragma unroll
      for (int o = 0; o < 32; ++o) a[o] += Wol[o][c] * m;
    }
    for (int o = 0; o < 32; ++o)
      Pb[((size_t)b * 256 + ob * 32 + o) * 256 + t] = (__bf16)a[o];
  }
  if (t < 32) {
    float s1 = 0.f, s2 = 0.f;
#pragma unroll 8
    for (int c = 0; c < 256; ++c) {
      s1 += Wol[t][c] * (cvec[b * 256 + c] - mu[b * 256 + c]);
      s2 += Wo[(ob * 32 + t) * 256 + c];
    }
    t1[b * 256 + ob * 32 + t] = s1;
    wsum[b * 256 + ob * 32 + t] = s2;
  }
}

// ---------------------------------------------------------------------------
// Kernel C: out = gamma*(P key + t1) + beta*wsum + bo (fused LN + conv).
// 1600 wgs batch-pinned to XCDs, 512 thr, 8 waves (4x2), 64KB LDS, 2 wg/CU.
// ---------------------------------------------------------------------------
__global__ __launch_bounds__(512, 4) void outf_k(
    const float* __restrict__ key, const __bf16* __restrict__ Pb,
    const float* __restrict__ t1, const float* __restrict__ wsum,
    const float* __restrict__ bo, const float* __restrict__ gamma,
    const float* __restrict__ beta, float* __restrict__ out) {
  __shared__ __align__(16) __bf16 Bt[128 * 256];  // [l][c], XOR-swizzled, 64KB
  const int bid = blockIdx.x;
  const int b = bid & 7, lt = bid >> 3, l0 = lt * 128;  // batch -> XCD pin
  const int tid = threadIdx.x, w = tid >> 6, lane = tid & 63;
  const int wr = w >> 1, wc = w & 1;
  const int lr = lane & 15, g = lane >> 4;
  const float* Kb = key + (size_t)b * NCH * LROW;

  // stage: thread = (channel c, l-half seg); 16x f32x4 contiguous per lane
  {
    const int c = tid & 255, seg = tid >> 8;
    const int uc = c >> 3, cb2 = (c & 7) * 2;
    const float* src = Kb + (size_t)c * LROW + l0 + seg * 64;
#pragma unroll
    for (int i = 0; i < 16; ++i) {
      f32x4 v = *(const f32x4*)(src + i * 4);
#pragma unroll
      for (int j = 0; j < 4; ++j) {
        const int l = seg * 64 + i * 4 + j;
        *(__bf16*)((char*)Bt + l * 512 + ((uc ^ (l & 7)) << 4) + cb2) = (__bf16)v[j];
      }
    }
  }
  __syncthreads();

  const f32x4 zero = {0.f, 0.f, 0.f, 0.f};
  f32x4 acc[4][4];
#pragma unroll
  for (int i = 0; i < 4; ++i)
#pragma unroll
    for (int j = 0; j < 4; ++j) acc[i][j] = zero;

  const __bf16* Pbase = Pb + (size_t)b * 65536;
#pragma unroll
  for (int ks = 0; ks < 8; ++ks) {
    bf16x8 af[4];
#pragma unroll
    for (int i = 0; i < 4; ++i) {
      const int row = wr * 64 + i * 16 + lr;
      af[i] = *(const bf16x8*)(Pbase + (size_t)row * 256 + ks * 32 + g * 8);
    }
#pragma unroll
    for (int j = 0; j < 4; ++j) {
      const int col = wc * 64 + j * 16 + lr;
      const int unit = ks * 4 + g;
      bf16x8 bfj = *(const bf16x8*)((const char*)Bt + col * 512 + ((unit ^ (col & 7)) << 4));
#pragma unroll
      for (int i = 0; i < 4; ++i)
        acc[i][j] = __builtin_amdgcn_mfma_f32_16x16x32_bf16(af[i], bfj, acc[i][j], 0, 0, 0);
    }
  }

  // lean epilogue: i/r outer (row scalars live briefly), j inner
#pragma unroll
  for (int i = 0; i < 4; ++i)
#pragma unroll
    for (int r = 0; r < 4; ++r) {
      const int row = wr * 64 + i * 16 + g * 4 + r;
      const float t1v = t1[b * 256 + row];
      const float wsv = wsum[b * 256 + row];
      const float bov = bo[row];
      const size_t ro = ((size_t)b * 256 + row) * LROW + l0;
#pragma unroll
      for (int j = 0; j < 4; ++j) {
        const int cl = wc * 64 + j * 16 + lr;
        out[ro + cl] = gamma[l0 + cl] * (acc[i][j][r] + t1v) + beta[l0 + cl] * wsv + bov;
      }
    }
}

// ---------------------------------------------------------------------------
extern "C" void kernel_launch(void* const* d_in, const int* in_sizes, int n_in,
                              void* d_out, int out_size, void* d_ws, size_t ws_size,
                              hipStream_t stream) {
  const float* query = (const float*)d_in[0];
  const float* key   = (const float*)d_in[1];
  const float* Wq = (const float*)d_in[2];
  const float* bq = (const float*)d_in[3];
  const float* Wk = (const float*)d_in[4];
  const float* bk = (const float*)d_in[5];
  const float* Wv = (const float*)d_in[6];
  const float* bv = (const float*)d_in[7];
  const float* Wo = (const float*)d_in[8];
  const float* bo = (const float*)d_in[9];
  const float* gamma = (const float*)d_in[10];
  const float* beta  = (const float*)d_in[11];
  float* out = (float*)d_out;

  // Workspace: base layout only (~7.4MB)
  float* ws = (float*)d_ws;
  float* G    = ws;                  // 524288
  float* Gkk  = G + 524288;          // 524288
  float* sq   = Gkk + 524288;        // 2048
  float* sk   = sq + 2048;           // 2048
  float* M    = sk + 2048;           // 524288
  float* cvec = M + 524288;          // 2048
  float* mu   = cvec + 2048;         // 2048
  float* inv  = mu + 2048;           // 2048
  float* t1   = inv + 2048;          // 2048
  float* wsum = t1 + 2048;           // 2048
  __bf16* Pb  = (__bf16*)(wsum + 2048);  // 524288 bf16

  // Gram partials live in D_OUT (33.5MB of its 209MB), fragment-flat layout;
  // outf_k overwrites all of d_out at the very end.
  float* Pp = out;

  hipMemsetAsync(sq, 0, 4096 * sizeof(float), stream);  // sq+sk (row-sum atomics)
  gram_k<<<512, 256, 0, stream>>>(query, key, Pp, sq, sk);
  reduce_k<<<1024, 256, 0, stream>>>(Pp, G, Gkk);
  attn_k<<<64, 256, 0, stream>>>(G, sq, sk, Wq, bq, Wk, bk, Wv, bv, M, cvec);
  stats_k<<<64, 256, 0, stream>>>(Gkk, M, sk, cvec, mu, inv);
  pmat_k<<<64, 256, 0, stream>>>(M, Wo, inv, cvec, mu, Pb, t1, wsum);
  outf_k<<<1600, 512, 0, stream>>>(key, Pb, t1, wsum, bo, gamma, beta, out);
}